// Round 7
// baseline (220.832 us; speedup 1.0000x reference)
//
#include <hip/hip_runtime.h>
#include <hip/hip_bf16.h>

#define NB 32
#define NN 1024
#define DINR 144

typedef __attribute__((ext_vector_type(4))) float f4;
typedef __attribute__((ext_vector_type(8))) short s8;

// ws float offsets
#define OFF_B0  (0u)
#define OFF_B1  (1u*NB*64*NN)
#define OFF_C   (2u*NB*64*NN)
#define OFF_UPA (3u*NB*64*NN)                 // B-part partials (ping)
#define OFF_UPB (OFF_UPA + NB*32*1024u)       // B-part partials (pong)
#define OFF_UPC (OFF_UPB + NB*32*1024u)       // A-part partials (static)
#define OFF_UC  (OFF_UPC + NB*32*1024u)       // combined U (per layer)
#define OFF_NS  (OFF_UC + NB*1024u)

static __device__ __forceinline__ unsigned short bf16u(float f) {
  __hip_bfloat16 h = __float2bfloat16(f);
  return *reinterpret_cast<unsigned short*>(&h);
}

// ---------------------------------------------------------------------------
// k_init  (unchanged from R5 — measured < 45 us)
// ---------------------------------------------------------------------------
__global__ __launch_bounds__(256) void k_init(
    const float* __restrict__ x, const float* __restrict__ emb,
    float* __restrict__ Bt, float* __restrict__ UpC, float* __restrict__ UpB,
    int* __restrict__ nstar)
{
  __shared__ union {
    unsigned int XT[NN * 8];
    struct {
      float xs[80 * 33];
      float es[512 * 4];
      float as[64 * 33];
    } d;
  } sm;
  int t = threadIdx.x;
  if (blockIdx.x < 1024) {
    int b = blockIdx.x >> 5;
    int ct = blockIdx.x & 31;
    int n0 = ct * 32;
    const float* xb = x + (size_t)b * DINR * NN;
    for (int idx = t; idx < 80 * 32; idx += 256) {
      int row = idx >> 5, col = idx & 31;
      sm.d.xs[row * 33 + col] = xb[row * NN + n0 + col];
    }
    f4* es4 = reinterpret_cast<f4*>(sm.d.es);
    const f4* E4g = reinterpret_cast<const f4*>(emb);
    for (int fj = t; fj < 512; fj += 256) {
      int j = fj >> 3, cc = fj & 7;
      es4[j * 8 + ((cc ^ (j >> 3)) & 7)] = E4g[fj];
    }
    __syncthreads();
    int c = t >> 3, g = t & 7;
    int n = n0 + c;
    bool live = (n < 1008);
    float a[8], bb[8];
    float xa[32];
    #pragma unroll
    for (int cc = 0; cc < 32; cc++) xa[cc] = sm.d.xs[(16 + cc) * 33 + c];
    #pragma unroll
    for (int jj = 0; jj < 8; jj++) {
      int j = g * 8 + jj;
      float acc = 0.f;
      #pragma unroll
      for (int cc = 0; cc < 8; cc++) {
        f4 e = es4[j * 8 + ((cc ^ g) & 7)];
        acc += e[0]*xa[4*cc] + e[1]*xa[4*cc+1] + e[2]*xa[4*cc+2] + e[3]*xa[4*cc+3];
      }
      a[jj] = acc;
    }
    #pragma unroll
    for (int cc = 0; cc < 32; cc++) xa[cc] = sm.d.xs[(48 + cc) * 33 + c];
    #pragma unroll
    for (int jj = 0; jj < 8; jj++) {
      int j = g * 8 + jj;
      float acc = 0.f;
      #pragma unroll
      for (int cc = 0; cc < 8; cc++) {
        f4 e = es4[j * 8 + ((cc ^ g) & 7)];
        acc += e[0]*xa[4*cc] + e[1]*xa[4*cc+1] + e[2]*xa[4*cc+2] + e[3]*xa[4*cc+3];
      }
      bb[jj] = acc;
    }
    f4 v0 = {bb[0], bb[1], bb[2], bb[3]};
    f4 v1 = {bb[4], bb[5], bb[6], bb[7]};
    f4* Bb = reinterpret_cast<f4*>(Bt + ((size_t)b * NN + n) * 64 + g * 8);
    Bb[0] = v0; Bb[1] = v1;
    #pragma unroll
    for (int jj = 0; jj < 8; jj++)
      sm.d.as[(g * 8 + jj) * 33 + c] = live ? a[jj] : 0.f;
    __syncthreads();
    float* upc = UpC + ((size_t)(b * 32 + ct)) * 1024;
    for (int idx = t; idx < 1024; idx += 256) {
      int j = idx >> 4, i = idx & 15;
      float s = 0.f;
      #pragma unroll
      for (int cc = 0; cc < 32; cc++) s += sm.d.as[j * 33 + cc] * sm.d.xs[i * 33 + cc];
      upc[idx] = s;
    }
    __syncthreads();
    #pragma unroll
    for (int jj = 0; jj < 8; jj++)
      sm.d.as[(g * 8 + jj) * 33 + c] = live ? bb[jj] : 0.f;
    __syncthreads();
    float* upb = UpB + ((size_t)(b * 32 + ct)) * 1024;
    for (int idx = t; idx < 1024; idx += 256) {
      int j = idx >> 4, i = idx & 15;
      float s = 0.f;
      #pragma unroll
      for (int cc = 0; cc < 32; cc++) s += sm.d.as[j * 33 + cc] * sm.d.xs[i * 33 + cc];
      upb[idx] = s;
    }
  } else {
    int a = blockIdx.x - 1024;
    int b = a >> 4;
    int mg = a & 15;
    const float* xb = x + (size_t)b * DINR * NN;
    #pragma unroll
    for (int rep = 0; rep < 4; rep++) {
      int n = t + (rep << 8);
      unsigned int pk[8];
      #pragma unroll
      for (int h = 0; h < 8; h++) {
        unsigned int u0 = __float_as_uint(xb[(2*h) * NN + n]);
        unsigned int u1 = __float_as_uint(xb[(2*h+1) * NN + n]);
        pk[h] = (u0 >> 16) | (u1 & 0xFFFF0000u);
      }
      #pragma unroll
      for (int h = 0; h < 8; h++) sm.XT[n * 8 + h] = pk[h];
    }
    __syncthreads();
    int w = t >> 6;
    int lane = t & 63;
    int r = lane & 15;
    int g = lane >> 4;
    int mt = mg * 64 + w * 16;
    s8 zero8 = {0,0,0,0,0,0,0,0};
    s8 afrag = zero8;
    if (g < 2) afrag = *reinterpret_cast<const s8*>(&sm.XT[(mt + r) * 8 + g * 4]);
    float bestv[4];
    int besti[4];
    #pragma unroll
    for (int j = 0; j < 4; j++) { bestv[j] = -3.4e38f; besti[j] = 0x7FFFFFFF; }
    for (int nt = 0; nt < 63; nt++) {
      s8 bfrag = zero8;
      if (g < 2) bfrag = *reinterpret_cast<const s8*>(&sm.XT[(nt*16 + r) * 8 + g * 4]);
      f4 acc = {0.f, 0.f, 0.f, 0.f};
      acc = __builtin_amdgcn_mfma_f32_16x16x32_bf16(afrag, bfrag, acc, 0, 0, 0);
      int n = nt * 16 + r;
      #pragma unroll
      for (int j = 0; j < 4; j++) {
        float v = acc[j];
        bool better = (v > bestv[j]) || (v == bestv[j] && n < besti[j]);
        if (better) { bestv[j] = v; besti[j] = n; }
      }
    }
    #pragma unroll
    for (int s = 1; s < 16; s <<= 1) {
      #pragma unroll
      for (int j = 0; j < 4; j++) {
        float ov = __shfl_xor(bestv[j], s, 64);
        int   oi = __shfl_xor(besti[j], s, 64);
        bool better = (ov > bestv[j]) || (ov == bestv[j] && oi < besti[j]);
        if (better) { bestv[j] = ov; besti[j] = oi; }
      }
    }
    if (r == 0) {
      #pragma unroll
      for (int j = 0; j < 4; j++)
        nstar[b * NN + mt + g * 4 + j] = besti[j];
    }
  }
}

// ---------------------------------------------------------------------------
// k_comb: Uc[b][j][i] = alpha[l][j] * (sum UpC chunks - sum UpB chunks)
// ---------------------------------------------------------------------------
__global__ __launch_bounds__(256) void k_comb(
    const float* __restrict__ UpC, const float* __restrict__ UpB, int ncb,
    const float* __restrict__ alpha, int l, float* __restrict__ Uc)
{
  int b = blockIdx.x >> 2;
  int idx = ((blockIdx.x & 3) << 8) + threadIdx.x;
  const float* pc = UpC + (size_t)b * 32 * 1024 + idx;
  const float* pb = UpB + (size_t)b * ncb * 1024 + idx;
  float sa = 0.f, sb = 0.f;
  #pragma unroll 8
  for (int ch = 0; ch < 32; ch++) sa += pc[ch * 1024];
  for (int ch = 0; ch < ncb; ch++) sb += pb[ch * 1024];
  Uc[(size_t)b * 1024 + idx] = alpha[l * 64 + (idx >> 4)] * (sa - sb);
}

// ---------------------------------------------------------------------------
// k_update: 512 threads, 64-col tiles, wave-uniform j (SGPR E/U rows).
// grid 512 = 32 b x 16 tiles. lane=col, wave w owns j in [8w,8w+8).
//  A: cn = Cin + sc*U@X (global r/m/w); logits partials -> LDS atomicAdd
//  softmax lane-local; B-update SGPR-E x reg-p; w -> Ws
//  Up chunk via MFMA 16x16x32 bf16 (waves 0-3)
// ---------------------------------------------------------------------------
__global__ __launch_bounds__(512) void k_update(
    const float* __restrict__ x, const float* __restrict__ emb,
    const float* __restrict__ kpp, const float* __restrict__ Uc,
    const int* __restrict__ nstar,
    const float* __restrict__ Cin, size_t cbs, float* __restrict__ Cout,
    const float* __restrict__ Bin, float* __restrict__ Bout,
    float* __restrict__ Upout, int last, float* __restrict__ out)
{
  __shared__ float Lg[64 * 33];          // logit accumulators [col][cat]
  __shared__ float Ws[64 * 66];          // masked Bout rows [j][col]
  __shared__ unsigned short Xb[16 * 64]; // bf16 X, XOR-swizzled rows
  int t = threadIdx.x;
  int b = blockIdx.x >> 4;
  int mt = blockIdx.x & 15;
  int n0 = mt * 64;
  int lane = t & 63;
  int w = t >> 6;
  int c = lane;
  int m = n0 + c;
  const float* xb = x + (size_t)b * DINR * NN;

  for (int i = t; i < 64 * 33; i += 512) Lg[i] = 0.f;
  // stage Xb (bf16, row-swizzled)
  {
    int i = t >> 5, c0 = (t & 31) * 2;
    float f0 = xb[i * NN + n0 + c0];
    float f1 = xb[i * NN + n0 + c0 + 1];
    unsigned int u = (unsigned int)bf16u(f0) | ((unsigned int)bf16u(f1) << 16);
    int byte = (i * 128 + c0 * 2) ^ ((i & 7) << 4);
    *reinterpret_cast<unsigned int*>(reinterpret_cast<char*>(Xb) + byte) = u;
  }
  float X[16];
  #pragma unroll
  for (int i = 0; i < 16; i++) X[i] = xb[i * NN + m];
  __syncthreads();

  int jw = __builtin_amdgcn_readfirstlane(w * 8);
  float sc = kpp[0] * (1.0f / 1008.0f);
  // ---- phase A: C update + logit partials ----
  {
    float lg[32];
    #pragma unroll
    for (int k = 0; k < 32; k++) lg[k] = 0.f;
    #pragma unroll
    for (int jj = 0; jj < 8; jj++) {
      int j = jw + jj;
      const float* Ur = Uc + ((size_t)b * 64 + j) * 16;
      const float* Er = emb + j * 32;
      float d = 0.f;
      #pragma unroll
      for (int i = 0; i < 16; i++) d += Ur[i] * X[i];
      float cn = Cin[(size_t)b * cbs + (size_t)j * NN + m] + sc * d;
      if (!last) Cout[(size_t)b * 64 * NN + (size_t)j * NN + m] = cn;
      #pragma unroll
      for (int k = 0; k < 32; k++) lg[k] = fmaf(Er[k], cn, lg[k]);
    }
    #pragma unroll
    for (int k = 0; k < 32; k++) atomicAdd(&Lg[c * 33 + k], lg[k]);
  }
  __syncthreads();

  // ---- softmax (lane-local, redundant across waves) ----
  float p[32];
  #pragma unroll
  for (int k = 0; k < 32; k++) p[k] = Lg[c * 33 + k];
  float mx = p[0];
  #pragma unroll
  for (int k = 1; k < 32; k++) mx = fmaxf(mx, p[k]);
  float ss = 0.f;
  #pragma unroll
  for (int k = 0; k < 32; k++) { p[k] = __expf(p[k] - mx); ss += p[k]; }
  float inv = 1.0f / ss;
  #pragma unroll
  for (int k = 0; k < 32; k++) p[k] *= inv;

  if (last) {
    if (w == 0) {
      float* lo = out + ((size_t)b * NN + m) * 32;
      float* po = lo + (size_t)NB * NN * 32;
      #pragma unroll
      for (int q = 0; q < 8; q++) {
        f4 vl = {Lg[c*33 + 4*q], Lg[c*33 + 4*q+1], Lg[c*33 + 4*q+2], Lg[c*33 + 4*q+3]};
        f4 vp = {p[4*q], p[4*q+1], p[4*q+2], p[4*q+3]};
        *reinterpret_cast<f4*>(lo + 4*q) = vl;
        *reinterpret_cast<f4*>(po + 4*q) = vp;
      }
    }
    return;
  }

  // ---- B update (rows jw..jw+7 of column m) ----
  {
    int nst = nstar[b * NN + m];
    const f4* BC = reinterpret_cast<const f4*>(Bin + ((size_t)b * NN + m) * 64 + jw);
    const f4* BG = reinterpret_cast<const f4*>(Bin + ((size_t)b * NN + nst) * 64 + jw);
    f4* BO = reinterpret_cast<f4*>(Bout + ((size_t)b * NN + m) * 64 + jw);
    const float invM = 1.0f / 1008.0f;
    bool live = (m < 1008);
    #pragma unroll
    for (int jq = 0; jq < 2; jq++) {
      f4 bc = BC[jq], bg = BG[jq], vo;
      #pragma unroll
      for (int kk = 0; kk < 4; kk++) {
        int j = jw + jq * 4 + kk;
        const float* Er = emb + j * 32;
        float v = fmaf(bg[kk], -invM, bc[kk]);
        #pragma unroll
        for (int k = 0; k < 32; k++) v = fmaf(Er[k], p[k], v);
        vo[kk] = v;
        Ws[j * 66 + c] = live ? v : 0.f;
      }
      BO[jq] = vo;
    }
  }
  __syncthreads();

  // ---- Up chunk = w @ X^T via MFMA (waves 0-3, m-tile = w) ----
  if (w < 4) {
    int m0 = w * 16;
    int r = lane & 15, q = lane >> 4;
    f4 acc = {0.f, 0.f, 0.f, 0.f};
    #pragma unroll
    for (int ks = 0; ks < 2; ks++) {
      union { s8 v; unsigned short u[8]; } A;
      #pragma unroll
      for (int e = 0; e < 8; e++)
        A.u[e] = bf16u(Ws[(m0 + r) * 66 + ks * 32 + q * 8 + e]);
      int byteb = (r * 128 + ks * 64 + q * 16) ^ ((r & 7) << 4);
      s8 bfrag = *reinterpret_cast<const s8*>(
          reinterpret_cast<const char*>(Xb) + byteb);
      acc = __builtin_amdgcn_mfma_f32_16x16x32_bf16(A.v, bfrag, acc, 0, 0, 0);
    }
    float* upb = Upout + ((size_t)(b * 16 + mt)) * 1024;
    #pragma unroll
    for (int reg = 0; reg < 4; reg++)
      upb[(m0 + q * 4 + reg) * 16 + r] = acc[reg];
  }
}

extern "C" void kernel_launch(void* const* d_in, const int* in_sizes, int n_in,
                              void* d_out, int out_size, void* d_ws, size_t ws_size,
                              hipStream_t stream)
{
  const float* x     = (const float*)d_in[0];
  const float* alpha = (const float*)d_in[1];
  const float* kp    = (const float*)d_in[2];
  const float* emb   = (const float*)d_in[3];
  float* ws = (float*)d_ws;
  float* B0  = ws + OFF_B0;
  float* B1  = ws + OFF_B1;
  float* C   = ws + OFF_C;
  float* UpA = ws + OFF_UPA;
  float* UpB = ws + OFF_UPB;
  float* UpC = ws + OFF_UPC;
  float* Uc  = ws + OFF_UC;
  int*   ns  = (int*)(ws + OFF_NS);
  float* out = (float*)d_out;

  k_init<<<1536, 256, 0, stream>>>(x, emb, B0, UpC, UpA, ns);
  // layer 0: Cin = x[80:144], B0->B1, B-part partials UpA (32 chunks) -> UpB (16)
  k_comb<<<128, 256, 0, stream>>>(UpC, UpA, 32, alpha, 0, Uc);
  k_update<<<512, 512, 0, stream>>>(x, emb, kp, Uc, ns,
                                    x + 80 * NN, (size_t)DINR * NN, C,
                                    B0, B1, UpB, 0, out);
  // layer 1: B1->B0, UpB (16) -> UpA (16)
  k_comb<<<128, 256, 0, stream>>>(UpC, UpB, 16, alpha, 1, Uc);
  k_update<<<512, 512, 0, stream>>>(x, emb, kp, Uc, ns,
                                    C, (size_t)64 * NN, C,
                                    B1, B0, UpA, 0, out);
  // layer 2 (last): outputs only
  k_comb<<<128, 256, 0, stream>>>(UpC, UpA, 16, alpha, 2, Uc);
  k_update<<<512, 512, 0, stream>>>(x, emb, kp, Uc, ns,
                                    C, (size_t)64 * NN, C,
                                    B0, B1, UpB, 1, out);
}

// Round 8
// 176.080 us; speedup vs baseline: 1.2542x; 1.2542x over previous
//
#include <hip/hip_runtime.h>
#include <hip/hip_bf16.h>

#define NB 32
#define NN 1024
#define DINR 144

typedef __attribute__((ext_vector_type(4))) float f4;
typedef __attribute__((ext_vector_type(8))) short s8;

// ws float offsets
#define OFF_B0  (0u)
#define OFF_B1  (1u*NB*64*NN)
#define OFF_C   (2u*NB*64*NN)
#define OFF_UPA (3u*NB*64*NN)                 // B-part partials (ping)
#define OFF_UPB (OFF_UPA + NB*32*1024u)       // B-part partials (pong)
#define OFF_UPC (OFF_UPB + NB*32*1024u)       // A-part partials (static)
#define OFF_UC  (OFF_UPC + NB*32*1024u)       // combined U (per layer)
#define OFF_NS  (OFF_UC + NB*1024u)

static __device__ __forceinline__ unsigned short bf16u(float f) {
  __hip_bfloat16 h = __float2bfloat16(f);
  return *reinterpret_cast<unsigned short*>(&h);
}

// build an 8-bf16 MFMA fragment from 8 consecutive f32 in LDS (16B-aligned)
static __device__ __forceinline__ s8 frag8(const float* p) {
  f4 lo = *reinterpret_cast<const f4*>(p);
  f4 hi = *reinterpret_cast<const f4*>(p + 4);
  union { s8 v; unsigned short u[8]; } F;
  F.u[0] = bf16u(lo[0]); F.u[1] = bf16u(lo[1]);
  F.u[2] = bf16u(lo[2]); F.u[3] = bf16u(lo[3]);
  F.u[4] = bf16u(hi[0]); F.u[5] = bf16u(hi[1]);
  F.u[6] = bf16u(hi[2]); F.u[7] = bf16u(hi[3]);
  return F.v;
}

// ---------------------------------------------------------------------------
// k_init
//  blocks [0,1024): 32-col slab: A/B0 via E@x; B0 col-major out;
//    UpC chunk = a@X^T and UpB chunk = b0@X^T via MFMA 16x16x32 bf16
//  blocks [1024,1536): nstar = argmax_{n<1008} X[:,m]·X[:,n]  (bf16 MFMA)
// ---------------------------------------------------------------------------
__global__ __launch_bounds__(256) void k_init(
    const float* __restrict__ x, const float* __restrict__ emb,
    float* __restrict__ Bt, float* __restrict__ UpC, float* __restrict__ UpB,
    int* __restrict__ nstar)
{
  __shared__ union {
    unsigned int XT[NN * 8];                 // 32768 B (argmax part)
    struct {
      float xs[80 * 36];                     // 11520 B (16B-aligned rows)
      float es[512 * 4];                     // 8192 B
      float as[64 * 36];                     // 9216 B
    } d;
  } sm;
  int t = threadIdx.x;
  if (blockIdx.x < 1024) {
    int b = blockIdx.x >> 5;
    int ct = blockIdx.x & 31;
    int n0 = ct * 32;
    const float* xb = x + (size_t)b * DINR * NN;
    for (int idx = t; idx < 80 * 32; idx += 256) {
      int row = idx >> 5, col = idx & 31;
      sm.d.xs[row * 36 + col] = xb[row * NN + n0 + col];
    }
    f4* es4 = reinterpret_cast<f4*>(sm.d.es);
    const f4* E4g = reinterpret_cast<const f4*>(emb);
    for (int fj = t; fj < 512; fj += 256) {
      int j = fj >> 3, cc = fj & 7;
      es4[j * 8 + ((cc ^ (j >> 3)) & 7)] = E4g[fj];
    }
    __syncthreads();
    int c = t >> 3, g = t & 7;
    int n = n0 + c;
    bool live = (n < 1008);
    float a[8], bb[8];
    float xa[32];
    #pragma unroll
    for (int cc = 0; cc < 32; cc++) xa[cc] = sm.d.xs[(16 + cc) * 36 + c];
    #pragma unroll
    for (int jj = 0; jj < 8; jj++) {
      int j = g * 8 + jj;
      float acc = 0.f;
      #pragma unroll
      for (int cc = 0; cc < 8; cc++) {
        f4 e = es4[j * 8 + ((cc ^ g) & 7)];
        acc += e[0]*xa[4*cc] + e[1]*xa[4*cc+1] + e[2]*xa[4*cc+2] + e[3]*xa[4*cc+3];
      }
      a[jj] = acc;
    }
    #pragma unroll
    for (int cc = 0; cc < 32; cc++) xa[cc] = sm.d.xs[(48 + cc) * 36 + c];
    #pragma unroll
    for (int jj = 0; jj < 8; jj++) {
      int j = g * 8 + jj;
      float acc = 0.f;
      #pragma unroll
      for (int cc = 0; cc < 8; cc++) {
        f4 e = es4[j * 8 + ((cc ^ g) & 7)];
        acc += e[0]*xa[4*cc] + e[1]*xa[4*cc+1] + e[2]*xa[4*cc+2] + e[3]*xa[4*cc+3];
      }
      bb[jj] = acc;
    }
    f4 v0 = {bb[0], bb[1], bb[2], bb[3]};
    f4 v1 = {bb[4], bb[5], bb[6], bb[7]};
    f4* Bb = reinterpret_cast<f4*>(Bt + ((size_t)b * NN + n) * 64 + g * 8);
    Bb[0] = v0; Bb[1] = v1;
    // UpC chunk via MFMA
    #pragma unroll
    for (int jj = 0; jj < 8; jj++)
      sm.d.as[(g * 8 + jj) * 36 + c] = live ? a[jj] : 0.f;
    __syncthreads();
    {
      int lane = t & 63, w = t >> 6;
      int r = lane & 15, q = lane >> 4;
      int jw = w * 16;
      s8 af = frag8(&sm.d.as[(jw + r) * 36 + q * 8]);
      s8 bf = frag8(&sm.d.xs[r * 36 + q * 8]);
      f4 acc = {0.f, 0.f, 0.f, 0.f};
      acc = __builtin_amdgcn_mfma_f32_16x16x32_bf16(af, bf, acc, 0, 0, 0);
      float* upc = UpC + ((size_t)(b * 32 + ct)) * 1024;
      #pragma unroll
      for (int reg = 0; reg < 4; reg++)
        upc[(jw + q * 4 + reg) * 16 + r] = acc[reg];
    }
    __syncthreads();
    // UpB chunk via MFMA
    #pragma unroll
    for (int jj = 0; jj < 8; jj++)
      sm.d.as[(g * 8 + jj) * 36 + c] = live ? bb[jj] : 0.f;
    __syncthreads();
    {
      int lane = t & 63, w = t >> 6;
      int r = lane & 15, q = lane >> 4;
      int jw = w * 16;
      s8 af = frag8(&sm.d.as[(jw + r) * 36 + q * 8]);
      s8 bf = frag8(&sm.d.xs[r * 36 + q * 8]);
      f4 acc = {0.f, 0.f, 0.f, 0.f};
      acc = __builtin_amdgcn_mfma_f32_16x16x32_bf16(af, bf, acc, 0, 0, 0);
      float* upb = UpB + ((size_t)(b * 32 + ct)) * 1024;
      #pragma unroll
      for (int reg = 0; reg < 4; reg++)
        upb[(jw + q * 4 + reg) * 16 + r] = acc[reg];
    }
  } else {
    int a = blockIdx.x - 1024;
    int b = a >> 4;
    int mg = a & 15;
    const float* xb = x + (size_t)b * DINR * NN;
    #pragma unroll
    for (int rep = 0; rep < 4; rep++) {
      int n = t + (rep << 8);
      unsigned int pk[8];
      #pragma unroll
      for (int h = 0; h < 8; h++) {
        unsigned int u0 = __float_as_uint(xb[(2*h) * NN + n]);
        unsigned int u1 = __float_as_uint(xb[(2*h+1) * NN + n]);
        pk[h] = (u0 >> 16) | (u1 & 0xFFFF0000u);
      }
      #pragma unroll
      for (int h = 0; h < 8; h++) sm.XT[n * 8 + h] = pk[h];
    }
    __syncthreads();
    int w = t >> 6;
    int lane = t & 63;
    int r = lane & 15;
    int g = lane >> 4;
    int mt = mg * 64 + w * 16;
    s8 zero8 = {0,0,0,0,0,0,0,0};
    s8 afrag = zero8;
    if (g < 2) afrag = *reinterpret_cast<const s8*>(&sm.XT[(mt + r) * 8 + g * 4]);
    float bestv[4];
    int besti[4];
    #pragma unroll
    for (int j = 0; j < 4; j++) { bestv[j] = -3.4e38f; besti[j] = 0x7FFFFFFF; }
    for (int nt = 0; nt < 63; nt++) {
      s8 bfrag = zero8;
      if (g < 2) bfrag = *reinterpret_cast<const s8*>(&sm.XT[(nt*16 + r) * 8 + g * 4]);
      f4 acc = {0.f, 0.f, 0.f, 0.f};
      acc = __builtin_amdgcn_mfma_f32_16x16x32_bf16(afrag, bfrag, acc, 0, 0, 0);
      int n = nt * 16 + r;
      #pragma unroll
      for (int j = 0; j < 4; j++) {
        float v = acc[j];
        bool better = (v > bestv[j]) || (v == bestv[j] && n < besti[j]);
        if (better) { bestv[j] = v; besti[j] = n; }
      }
    }
    #pragma unroll
    for (int s = 1; s < 16; s <<= 1) {
      #pragma unroll
      for (int j = 0; j < 4; j++) {
        float ov = __shfl_xor(bestv[j], s, 64);
        int   oi = __shfl_xor(besti[j], s, 64);
        bool better = (ov > bestv[j]) || (ov == bestv[j] && oi < besti[j]);
        if (better) { bestv[j] = ov; besti[j] = oi; }
      }
    }
    if (r == 0) {
      #pragma unroll
      for (int j = 0; j < 4; j++)
        nstar[b * NN + mt + g * 4 + j] = besti[j];
    }
  }
}

// ---------------------------------------------------------------------------
// k_comb: Uc[b][j][i] = alpha[l][j] * (sum UpC chunks - sum UpB chunks)
// ---------------------------------------------------------------------------
__global__ __launch_bounds__(256) void k_comb(
    const float* __restrict__ UpC, const float* __restrict__ UpB, int ncb,
    const float* __restrict__ alpha, int l, float* __restrict__ Uc)
{
  int b = blockIdx.x >> 2;
  int idx = ((blockIdx.x & 3) << 8) + threadIdx.x;
  const float* pc = UpC + (size_t)b * 32 * 1024 + idx;
  const float* pb = UpB + (size_t)b * ncb * 1024 + idx;
  float sa = 0.f, sb = 0.f;
  #pragma unroll 8
  for (int ch = 0; ch < 32; ch++) sa += pc[ch * 1024];
  for (int ch = 0; ch < ncb; ch++) sb += pb[ch * 1024];
  Uc[(size_t)b * 1024 + idx] = alpha[l * 64 + (idx >> 4)] * (sa - sb);
}

// ---------------------------------------------------------------------------
// k_update: 256 threads (4 waves), 64-col tiles, wave-uniform j (SGPR E/U).
// grid 512 = 32 b x 16 tiles. lane=col, wave w owns j in [16w,16w+16).
// ---------------------------------------------------------------------------
__global__ __launch_bounds__(256, 3) void k_update(
    const float* __restrict__ x, const float* __restrict__ emb,
    const float* __restrict__ kpp, const float* __restrict__ Uc,
    const int* __restrict__ nstar,
    const float* __restrict__ Cin, size_t cbs, float* __restrict__ Cout,
    const float* __restrict__ Bin, float* __restrict__ Bout,
    float* __restrict__ Upout, int last, float* __restrict__ out)
{
  __shared__ float Lg[64 * 33];   // logit accumulators [col][cat]
  __shared__ float Ws[64 * 68];   // masked Bout rows [j][col], 16B-aligned rows
  __shared__ float Xf[16 * 68];   // X rows [i][col]
  int t = threadIdx.x;
  int b = blockIdx.x >> 4;
  int mt = blockIdx.x & 15;
  int n0 = mt * 64;
  int lane = t & 63;
  int w = t >> 6;
  int c = lane;
  int m = n0 + c;
  const float* xb = x + (size_t)b * DINR * NN;

  for (int i = t; i < 64 * 33; i += 256) Lg[i] = 0.f;
  for (int s = t; s < 16 * 64; s += 256) {
    int i = s >> 6, c0 = s & 63;
    Xf[i * 68 + c0] = xb[i * NN + n0 + c0];
  }
  __syncthreads();

  float X[16];
  #pragma unroll
  for (int i = 0; i < 16; i++) X[i] = Xf[i * 68 + c];

  int jw = __builtin_amdgcn_readfirstlane(w * 16);
  float sc = kpp[0] * (1.0f / 1008.0f);
  // ---- phase A: C update + logit partials (j = jw..jw+15) ----
  {
    float lg[32];
    #pragma unroll
    for (int k = 0; k < 32; k++) lg[k] = 0.f;
    #pragma unroll
    for (int jj = 0; jj < 16; jj++) {
      int j = jw + jj;
      const float* Ur = Uc + ((size_t)b * 64 + j) * 16;
      const float* Er = emb + j * 32;
      float d = 0.f;
      #pragma unroll
      for (int i = 0; i < 16; i++) d += Ur[i] * X[i];
      float cn = Cin[(size_t)b * cbs + (size_t)j * NN + m] + sc * d;
      if (!last) Cout[(size_t)b * 64 * NN + (size_t)j * NN + m] = cn;
      #pragma unroll
      for (int k = 0; k < 32; k++) lg[k] = fmaf(Er[k], cn, lg[k]);
    }
    #pragma unroll
    for (int k = 0; k < 32; k++) atomicAdd(&Lg[c * 33 + k], lg[k]);
  }
  __syncthreads();

  // ---- softmax (lane-local, redundant across the 4 waves) ----
  float p[32];
  #pragma unroll
  for (int k = 0; k < 32; k++) p[k] = Lg[c * 33 + k];
  float mx = p[0];
  #pragma unroll
  for (int k = 1; k < 32; k++) mx = fmaxf(mx, p[k]);
  float ss = 0.f;
  #pragma unroll
  for (int k = 0; k < 32; k++) { p[k] = __expf(p[k] - mx); ss += p[k]; }
  float inv = 1.0f / ss;
  #pragma unroll
  for (int k = 0; k < 32; k++) p[k] *= inv;

  if (last) {
    if (w == 0) {
      float* lo = out + ((size_t)b * NN + m) * 32;
      float* po = lo + (size_t)NB * NN * 32;
      #pragma unroll
      for (int q = 0; q < 8; q++) {
        f4 vl = {Lg[c*33 + 4*q], Lg[c*33 + 4*q+1], Lg[c*33 + 4*q+2], Lg[c*33 + 4*q+3]};
        f4 vp = {p[4*q], p[4*q+1], p[4*q+2], p[4*q+3]};
        *reinterpret_cast<f4*>(lo + 4*q) = vl;
        *reinterpret_cast<f4*>(po + 4*q) = vp;
      }
    }
    return;
  }

  // ---- B update (rows jw..jw+15 of column m) ----
  {
    int nst = nstar[b * NN + m];
    const f4* BC = reinterpret_cast<const f4*>(Bin + ((size_t)b * NN + m) * 64 + jw);
    const f4* BG = reinterpret_cast<const f4*>(Bin + ((size_t)b * NN + nst) * 64 + jw);
    f4* BO = reinterpret_cast<f4*>(Bout + ((size_t)b * NN + m) * 64 + jw);
    const float invM = 1.0f / 1008.0f;
    bool live = (m < 1008);
    #pragma unroll
    for (int jq = 0; jq < 4; jq++) {
      f4 bc = BC[jq], bg = BG[jq], vo;
      #pragma unroll
      for (int kk = 0; kk < 4; kk++) {
        int j = jw + jq * 4 + kk;
        const float* Er = emb + j * 32;
        float v = fmaf(bg[kk], -invM, bc[kk]);
        #pragma unroll
        for (int k = 0; k < 32; k++) v = fmaf(Er[k], p[k], v);
        vo[kk] = v;
        Ws[j * 68 + c] = live ? v : 0.f;
      }
      BO[jq] = vo;
    }
  }
  __syncthreads();

  // ---- Up chunk = w @ X^T via MFMA (all 4 waves; stripe jw) ----
  {
    int r = lane & 15, q = lane >> 4;
    f4 acc = {0.f, 0.f, 0.f, 0.f};
    #pragma unroll
    for (int ks = 0; ks < 2; ks++) {
      s8 af = frag8(&Ws[(jw + r) * 68 + ks * 32 + q * 8]);
      s8 bf = frag8(&Xf[r * 68 + ks * 32 + q * 8]);
      acc = __builtin_amdgcn_mfma_f32_16x16x32_bf16(af, bf, acc, 0, 0, 0);
    }
    float* upb = Upout + ((size_t)(b * 16 + mt)) * 1024;
    #pragma unroll
    for (int reg = 0; reg < 4; reg++)
      upb[(jw + q * 4 + reg) * 16 + r] = acc[reg];
  }
}

extern "C" void kernel_launch(void* const* d_in, const int* in_sizes, int n_in,
                              void* d_out, int out_size, void* d_ws, size_t ws_size,
                              hipStream_t stream)
{
  const float* x     = (const float*)d_in[0];
  const float* alpha = (const float*)d_in[1];
  const float* kp    = (const float*)d_in[2];
  const float* emb   = (const float*)d_in[3];
  float* ws = (float*)d_ws;
  float* B0  = ws + OFF_B0;
  float* B1  = ws + OFF_B1;
  float* C   = ws + OFF_C;
  float* UpA = ws + OFF_UPA;
  float* UpB = ws + OFF_UPB;
  float* UpC = ws + OFF_UPC;
  float* Uc  = ws + OFF_UC;
  int*   ns  = (int*)(ws + OFF_NS);
  float* out = (float*)d_out;

  k_init<<<1536, 256, 0, stream>>>(x, emb, B0, UpC, UpA, ns);
  // layer 0: Cin = x[80:144], B0->B1, UpA (32 chunks) -> UpB (16)
  k_comb<<<128, 256, 0, stream>>>(UpC, UpA, 32, alpha, 0, Uc);
  k_update<<<512, 256, 0, stream>>>(x, emb, kp, Uc, ns,
                                    x + 80 * NN, (size_t)DINR * NN, C,
                                    B0, B1, UpB, 0, out);
  // layer 1: B1->B0, UpB (16) -> UpA (16)
  k_comb<<<128, 256, 0, stream>>>(UpC, UpB, 16, alpha, 1, Uc);
  k_update<<<512, 256, 0, stream>>>(x, emb, kp, Uc, ns,
                                    C, (size_t)64 * NN, C,
                                    B1, B0, UpA, 0, out);
  // layer 2 (last): outputs only
  k_comb<<<128, 256, 0, stream>>>(UpC, UpA, 16, alpha, 2, Uc);
  k_update<<<512, 256, 0, stream>>>(x, emb, kp, Uc, ns,
                                    C, (size_t)64 * NN, C,
                                    B0, B1, UpB, 1, out);
}